// Round 3
// baseline (734.443 us; speedup 1.0000x reference)
//
#include <hip/hip_runtime.h>
#include <hip/hip_bf16.h>

// out[b] = mean_x( 0.5 - 0.5*tanh((x - bins[b]) * 2/bw) ), bw = 0.0625,
//          bins[b] = -2 + bw*b, b in [0,64)
// With t = (x+2)*16 (bin coordinate), per-element contribution to bin b is
//   sigma(4*(b - t)),  sigma = logistic.
// sigma(z) saturates to {0,1} for |z| >= 20, i.e. |b - t| >= 5. Per block:
//   1) fine LDS histogram of t (cell = 1/64 bin, t in [-5, 69), 4736 cells)
//   2) group sums (64 cells/group) + exclusive prefix -> count left of window
//   3) per bin: 640-cell sigmoid window, wave-reduce, one float atomicAdd
// Single kernel; no global histogram, no second dispatch.

#define NCELLS (74 * 64)        // 4736 cells, t in [-5, 69), width 1/64
#define NGROUPS 74
#define HIST_BLOCKS 1024
#define HIST_THREADS 256

__global__ void __launch_bounds__(HIST_THREADS)
fused_kernel(const float* __restrict__ x, float* __restrict__ out,
             int n, float invN)
{
    __shared__ unsigned hist[NCELLS];
    __shared__ unsigned gsum[NGROUPS];

    const int tid = threadIdx.x;
    for (int i = tid; i < NCELLS; i += HIST_THREADS) hist[i] = 0u;
    __syncthreads();

    // ---- phase 1: histogram (memory-bound, ~268 MB total read) ----
    const int n4 = n >> 2;
    const float4* __restrict__ x4 = (const float4*)x;
    const int gid    = blockIdx.x * HIST_THREADS + tid;
    const int stride = gridDim.x * HIST_THREADS;

    // cell index: f = floor((t + 5) * 64) = floor(x*1024 + 2368)  -- one FMA
    for (int i = gid; i < n4; i += stride) {
        float4 v = x4[i];
        int f0 = (int)floorf(fmaf(v.x, 1024.0f, 2368.0f));
        int f1 = (int)floorf(fmaf(v.y, 1024.0f, 2368.0f));
        int f2 = (int)floorf(fmaf(v.z, 1024.0f, 2368.0f));
        int f3 = (int)floorf(fmaf(v.w, 1024.0f, 2368.0f));
        f0 = min(max(f0, 0), NCELLS - 1);
        f1 = min(max(f1, 0), NCELLS - 1);
        f2 = min(max(f2, 0), NCELLS - 1);
        f3 = min(max(f3, 0), NCELLS - 1);
        atomicAdd(&hist[f0], 1u);
        atomicAdd(&hist[f1], 1u);
        atomicAdd(&hist[f2], 1u);
        atomicAdd(&hist[f3], 1u);
    }
    if (blockIdx.x == 0) {            // scalar tail (n%4), defensive
        int tail = n & 3;
        if (tid < tail) {
            float v = x[n4 * 4 + tid];
            int f = (int)floorf(fmaf(v, 1024.0f, 2368.0f));
            f = min(max(f, 0), NCELLS - 1);
            atomicAdd(&hist[f], 1u);
        }
    }
    __syncthreads();

    // ---- phase 2: group sums (rotated access: 2-way banks = free) ----
    if (tid < NGROUPS) {
        unsigned s = 0;
        int base = tid * 64;
        #pragma unroll 8
        for (int i = 0; i < 64; ++i) s += hist[base + ((i + tid) & 63)];
        gsum[tid] = s;
    }
    __syncthreads();
    if (tid == 0) {                   // exclusive prefix over 74 entries
        unsigned acc = 0;
        for (int k = 0; k < NGROUPS; ++k) {
            unsigned v = gsum[k]; gsum[k] = acc; acc += v;
        }
    }
    __syncthreads();

    // ---- phase 3: windowed sigmoid sums, one wave handles 16 bins ----
    // bin b window: cells f in [64b, 64b+640); cells f < 64b contribute 1.
    const int wave = tid >> 6;        // 0..3
    const int lane = tid & 63;
    for (int bb = 0; bb < 16; ++bb) {
        const int b = wave * 16 + bb;
        const int fbase = b << 6;
        const float zc = 4.0f * (float)b + 19.96875f;  // 4b + 20 - 1/32
        float acc = 0.0f;
        #pragma unroll
        for (int k = 0; k < 10; ++k) {
            int f = fbase + (k << 6) + lane;           // consecutive lanes -> 2-way banks
            float h = (float)hist[f];
            float z = fmaf((float)f, -0.0625f, zc);    // z = 4(b - t_center)
            float s = 1.0f / (1.0f + __expf(-z));
            acc = fmaf(h, s, acc);
        }
        #pragma unroll
        for (int m = 32; m > 0; m >>= 1) acc += __shfl_xor(acc, m, 64);
        if (lane == 0)
            atomicAdd(&out[b], (acc + (float)gsum[b]) * invN);
    }
}

extern "C" void kernel_launch(void* const* d_in, const int* in_sizes, int n_in,
                              void* d_out, int out_size, void* d_ws, size_t ws_size,
                              hipStream_t stream)
{
    const float* x = (const float*)d_in[0];
    const int n = in_sizes[0];
    float* out = (float*)d_out;

    // d_out is re-poisoned to 0xAA before every call; zero the 256 B output.
    hipMemsetAsync(d_out, 0, 64 * sizeof(float), stream);

    fused_kernel<<<HIST_BLOCKS, HIST_THREADS, 0, stream>>>(x, out, n, 1.0f / (float)n);
}

// Round 4
// 404.945 us; speedup vs baseline: 1.8137x; 1.8137x over previous
//
#include <hip/hip_runtime.h>
#include <hip/hip_bf16.h>

// out[b] = mean_x( 0.5 - 0.5*tanh((x - bins[b]) * 2/bw) ), bw = 0.0625,
//          bins[b] = -2 + bw*b, b in [0,64)
// t = (x+2)*16 (bin coordinate); element contribution to bin b = sigma(4(b-t)).
// sigma saturates to {0,1} for |b-t| >= 5  =>  per-block fine LDS histogram of
// t (cell = 1/64 bin, t in [-5,69), 4736 cells) is a sufficient statistic.
// Per block: hist -> group sums + exclusive prefix (count left of window) ->
// 640-cell sigmoid window per bin -> 64 fp32 partials stored PLAIN to ws.
// (R3 lesson: 65k fp32 atomicAdds onto 4 cache lines serialized ~340us.
//  Plain per-block stores + a tiny reduce kernel instead.)
// Second kernel: 64 blocks reduce 2048 partials each (double acc) -> out[b].

#define NCELLS (74 * 64)        // 4736 cells
#define NGROUPS 74
#define HIST_BLOCKS 2048        // 8 blocks/CU; LDS 19.5KB*8 = 156KB fits
#define HIST_THREADS 256
#define UNROLL 4

__global__ void __launch_bounds__(HIST_THREADS)
hist_kernel(const float* __restrict__ x, float* __restrict__ ws, int n)
{
    __shared__ unsigned hist[NCELLS];
    __shared__ unsigned gsum[NGROUPS];
    __shared__ float    part[64];

    const int tid = threadIdx.x;
    for (int i = tid; i < NCELLS; i += HIST_THREADS) hist[i] = 0u;
    __syncthreads();

    // ---- phase 1: histogram; 4 loads in flight per thread for MLP ----
    const int n4 = n >> 2;
    const float4* __restrict__ x4 = (const float4*)x;
    const int per_iter = HIST_BLOCKS * HIST_THREADS * UNROLL;
    // cell index: f = floor((t+5)*64) = floor(x*1024 + 2368)  -- one FMA
    for (int i0 = blockIdx.x * (HIST_THREADS * UNROLL) + tid; i0 < n4; i0 += per_iter) {
        float4 v[UNROLL];
        int    ok[UNROLL];
        #pragma unroll
        for (int u = 0; u < UNROLL; ++u) {
            int idx = i0 + u * HIST_THREADS;
            ok[u] = idx < n4;
            v[u] = ok[u] ? x4[idx] : make_float4(-100.f, -100.f, -100.f, -100.f);
        }
        #pragma unroll
        for (int u = 0; u < UNROLL; ++u) {
            if (!ok[u]) continue;
            int f0 = (int)floorf(fmaf(v[u].x, 1024.0f, 2368.0f));
            int f1 = (int)floorf(fmaf(v[u].y, 1024.0f, 2368.0f));
            int f2 = (int)floorf(fmaf(v[u].z, 1024.0f, 2368.0f));
            int f3 = (int)floorf(fmaf(v[u].w, 1024.0f, 2368.0f));
            f0 = min(max(f0, 0), NCELLS - 1);
            f1 = min(max(f1, 0), NCELLS - 1);
            f2 = min(max(f2, 0), NCELLS - 1);
            f3 = min(max(f3, 0), NCELLS - 1);
            atomicAdd(&hist[f0], 1u);
            atomicAdd(&hist[f1], 1u);
            atomicAdd(&hist[f2], 1u);
            atomicAdd(&hist[f3], 1u);
        }
    }
    if (blockIdx.x == 0) {            // scalar tail (n%4), defensive
        int tail = n & 3;
        if (tid < tail) {
            float vv = x[n4 * 4 + tid];
            int f = (int)floorf(fmaf(vv, 1024.0f, 2368.0f));
            f = min(max(f, 0), NCELLS - 1);
            atomicAdd(&hist[f], 1u);
        }
    }
    __syncthreads();

    // ---- phase 2: group sums (rotated: 2-way banks = free) + prefix ----
    if (tid < NGROUPS) {
        unsigned s = 0;
        int base = tid * 64;
        #pragma unroll 8
        for (int i = 0; i < 64; ++i) s += hist[base + ((i + tid) & 63)];
        gsum[tid] = s;
    }
    __syncthreads();
    if (tid == 0) {                   // exclusive prefix over 74 entries
        unsigned acc = 0;
        for (int k = 0; k < NGROUPS; ++k) {
            unsigned v2 = gsum[k]; gsum[k] = acc; acc += v2;
        }
    }
    __syncthreads();

    // ---- phase 3: windowed sigmoid, one wave per 16 bins ----
    const int wave = tid >> 6;        // 0..3
    const int lane = tid & 63;
    for (int bb = 0; bb < 16; ++bb) {
        const int b = wave * 16 + bb;
        const int fbase = b << 6;
        const float zc = 4.0f * (float)b + 19.96875f;  // 4b + 20 - 1/32
        float acc = 0.0f;
        #pragma unroll
        for (int k = 0; k < 10; ++k) {
            int f = fbase + (k << 6) + lane;           // consecutive lanes
            float h = (float)hist[f];
            float z = fmaf((float)f, -0.0625f, zc);    // z = 4(b - t_center)
            float s = 1.0f / (1.0f + __expf(-z));
            acc = fmaf(h, s, acc);
        }
        #pragma unroll
        for (int m = 32; m > 0; m >>= 1) acc += __shfl_xor(acc, m, 64);
        if (lane == 0) part[b] = acc + (float)gsum[b];
    }
    __syncthreads();
    // plain scattered stores (64 dwords/block) — no atomics anywhere
    if (tid < 64) ws[tid * HIST_BLOCKS + blockIdx.x] = part[tid];
}

__global__ void __launch_bounds__(256)
reduce_kernel(const float* __restrict__ ws, float* __restrict__ out, float invN)
{
    const int b = blockIdx.x;                // 64 blocks, one per bin
    const float* __restrict__ p = ws + b * HIST_BLOCKS;
    double sum = 0.0;
    for (int i = threadIdx.x; i < HIST_BLOCKS; i += 256) sum += (double)p[i];
    __shared__ double sd[256];
    sd[threadIdx.x] = sum;
    __syncthreads();
    for (int ofs = 128; ofs > 0; ofs >>= 1) {
        if (threadIdx.x < ofs) sd[threadIdx.x] += sd[threadIdx.x + ofs];
        __syncthreads();
    }
    if (threadIdx.x == 0) out[b] = (float)(sd[0] * (double)invN);
}

extern "C" void kernel_launch(void* const* d_in, const int* in_sizes, int n_in,
                              void* d_out, int out_size, void* d_ws, size_t ws_size,
                              hipStream_t stream)
{
    const float* x = (const float*)d_in[0];
    const int n = in_sizes[0];
    float* ws = (float*)d_ws;                // 64*HIST_BLOCKS floats = 512 KB

    hist_kernel<<<HIST_BLOCKS, HIST_THREADS, 0, stream>>>(x, ws, n);
    reduce_kernel<<<64, 256, 0, stream>>>(ws, (float*)d_out, 1.0f / (float)n);
}